// Round 12
// baseline (627.946 us; speedup 1.0000x reference)
//
#include <hip/hip_runtime.h>
#include <cstdint>
#include <cstddef>

constexpr int kN   = 50000;          // nodes
constexpr int kE   = 800000;         // edges (without self loops)
constexpr int kEt  = kE + kN;        // edges + self loops
constexpr float kSlope = 0.2f;       // leaky relu slope

typedef __attribute__((ext_vector_type(8))) short bf8_t;   // 8 bf16 = 4 VGPRs
typedef __attribute__((ext_vector_type(4))) float f4_t;

// ---------------- static device workspace (d_ws unused) ---------------------
__device__ __align__(16) unsigned short g_aggx_h[(size_t)kN * 512]; // agg of x, bf16 hi
__device__ __align__(16) unsigned short g_aggx_l[(size_t)kN * 512]; // bf16 lo residual
__device__ __align__(16) unsigned short g_w1t_h[4 * 128 * 128];     // W1^T per head, hi
__device__ __align__(16) unsigned short g_w1t_l[4 * 128 * 128];
__device__ __align__(16) unsigned short g_w2t_h[128 * 512];         // W2^T, hi
__device__ __align__(16) unsigned short g_w2t_l[128 * 512];
__device__ __align__(16) float g_h2  [(size_t)kN * 128];  // layer-2 pre-agg features
__device__ __align__(16) float g_es1[kN * 4];
__device__ __align__(16) float g_ed1[kN * 4];
__device__ float g_es2[kN];
__device__ float g_ed2[kN];
__device__ __align__(16) float g_p1s[4 * 128];  // folded W1_h @ a1_src_h
__device__ __align__(16) float g_p1d[4 * 128];
// CSR by destination:
__device__ int g_deg[kN];
__device__ int g_ptr[kN + 1];
__device__ int g_cur[kN];
__device__ int g_srcs[kEt];

__device__ __forceinline__ float lrelu(float x) { return x > 0.f ? x : kSlope * x; }

__device__ __forceinline__ bf8_t bf8_zero() {
  uint4 z = make_uint4(0u, 0u, 0u, 0u);
  return *(bf8_t*)&z;
}

// round-to-nearest-even f32 -> bf16
__device__ __forceinline__ unsigned short f2bf(float v, float& hi_f) {
  unsigned u = __float_as_uint(v);
  unsigned r = (u + 0x7FFFu + ((u >> 16) & 1u)) & 0xFFFF0000u;
  hi_f = __uint_as_float(r);
  return (unsigned short)(r >> 16);
}
__device__ __forceinline__ void split_bf(float v, unsigned short& h, unsigned short& l) {
  float hf, lf;
  h = f2bf(v, hf);
  l = f2bf(v - hf, lf);
}

// ------------------------- CSR build ----------------------------------------
__global__ __launch_bounds__(256) void k_zero_deg() {
  int i = blockIdx.x * 256 + threadIdx.x;
  if (i < kN) g_deg[i] = 0;
}

__global__ __launch_bounds__(256) void k_hist(const int* __restrict__ ei) {
  int e = blockIdx.x * 256 + threadIdx.x;
  if (e >= kEt) return;
  int d = (e < kE) ? ei[kE + e] : e - kE;
  atomicAdd(&g_deg[d], 1);
}

// single-block (1024 thr) exclusive scan -> g_ptr, g_cur
__global__ __launch_bounds__(1024) void k_scan() {
  __shared__ int s_sum[1024];
  const int t = threadIdx.x;
  const int chunk = (kN + 1023) / 1024;        // 49
  const int lo = t * chunk, hi = min(lo + chunk, kN);
  int sum = 0;
  for (int i = lo; i < hi; ++i) sum += g_deg[i];
  s_sum[t] = sum;
  __syncthreads();
  for (int off = 1; off < 1024; off <<= 1) {
    int xv = s_sum[t];
    int yv = (t >= off) ? s_sum[t - off] : 0;
    __syncthreads();
    s_sum[t] = xv + yv;
    __syncthreads();
  }
  int run = s_sum[t] - sum;
  for (int i = lo; i < hi; ++i) {
    g_ptr[i] = run;
    g_cur[i] = run;
    run += g_deg[i];
  }
  if (t == 1023) g_ptr[kN] = run;
}

__global__ __launch_bounds__(256) void k_scatter(const int* __restrict__ ei) {
  int e = blockIdx.x * 256 + threadIdx.x;
  if (e >= kEt) return;
  int s, d;
  if (e < kE) { s = ei[e]; d = ei[kE + e]; } else { s = d = e - kE; }
  int slot = atomicAdd(&g_cur[d], 1);
  g_srcs[slot] = s;
}

// ---- weight conversion: W1 -> per-head W1T hi/lo, W2 -> W2T hi/lo ----------
__global__ __launch_bounds__(256) void k_convw(const float* __restrict__ W1,
                                               const float* __restrict__ W2) {
  int gid = blockIdx.x * 256 + threadIdx.x;   // 0..131071
  if (gid < 65536) {
    int h = gid >> 14, rem = gid & 16383;
    int c = rem >> 7, j = rem & 127;
    float v = W1[(size_t)c * 512 + h * 128 + j];
    unsigned short hh, ll;
    split_bf(v, hh, ll);
    size_t o = ((size_t)h * 128 + j) * 128 + c;
    g_w1t_h[o] = hh; g_w1t_l[o] = ll;
  } else {
    int g2 = gid - 65536;
    int k = g2 >> 7, j = g2 & 127;
    float v = W2[(size_t)k * 128 + j];
    unsigned short hh, ll;
    split_bf(v, hh, ll);
    size_t o = (size_t)j * 512 + k;
    g_w2t_h[o] = hh; g_w2t_l[o] = ll;
  }
}

// ---- fold attention vectors through W1 ----
__global__ __launch_bounds__(256) void k_prep1(const float* __restrict__ W1,
    const float* __restrict__ a1s, const float* __restrict__ a1d) {
  int gid = blockIdx.x * 256 + threadIdx.x;
  if (gid >= 1024) return;
  int which = gid >> 9, idx = gid & 511;
  int h = idx >> 7, k = idx & 127;
  const float* a = which ? a1d : a1s;
  const float* wrow = W1 + (size_t)k * 512 + h * 128;
  float s = 0.f;
#pragma unroll 8
  for (int c = 0; c < 128; ++c) s += wrow[c] * a[h * 128 + c];
  (which ? g_p1d : g_p1s)[idx] = s;
}

// ---- layer-1 scores directly from x ----
__global__ __launch_bounds__(256) void k_scores1x(const float* __restrict__ x) {
  const int lane = threadIdx.x & 63;
  const int n = (blockIdx.x * 256 + threadIdx.x) >> 6;
  if (n >= kN) return;
  float x0 = x[(size_t)n * 128 + lane];
  float x1 = x[(size_t)n * 128 + 64 + lane];
  float s[4], d[4];
#pragma unroll
  for (int h = 0; h < 4; ++h) {
    s[h] = x0 * g_p1s[h * 128 + lane] + x1 * g_p1s[h * 128 + 64 + lane];
    d[h] = x0 * g_p1d[h * 128 + lane] + x1 * g_p1d[h * 128 + 64 + lane];
  }
#pragma unroll
  for (int off = 32; off > 0; off >>= 1) {
#pragma unroll
    for (int h = 0; h < 4; ++h) {
      s[h] += __shfl_down(s[h], off);
      d[h] += __shfl_down(d[h], off);
    }
  }
  if (lane == 0) {
    *(float4*)(g_es1 + (size_t)n * 4) = make_float4(s[0], s[1], s[2], s[3]);
    *(float4*)(g_ed1 + (size_t)n * 4) = make_float4(d[0], d[1], d[2], d[3]);
  }
}

// ---- layer-1 aggregation: 4 edges/iter (16-lane quarters), 2xfloat4/lane ---
__global__ __launch_bounds__(256) void k_agg1x(const float* __restrict__ x) {
  const int lane = threadIdx.x & 63;
  const int n = (blockIdx.x * 256 + threadIdx.x) >> 6;
  if (n >= kN) return;
  const int beg = g_ptr[n], end = g_ptr[n + 1];
  const float4 ed = *(const float4*)(g_ed1 + (size_t)n * 4);
  const int qt = lane >> 4, ql = lane & 15;
  float z0 = 0.f, z1 = 0.f, z2 = 0.f, z3 = 0.f;
  float acc[4][8] = {};
  for (int base = beg; base < end; base += 64) {
    const int cnt = min(64, end - base);
    int s = 0;
    float w0 = 0.f, w1 = 0.f, w2 = 0.f, w3 = 0.f;
    if (lane < cnt) {
      s = g_srcs[base + lane];
      float4 es = *(const float4*)(g_es1 + (size_t)s * 4);
      w0 = __expf(lrelu(es.x + ed.x));
      w1 = __expf(lrelu(es.y + ed.y));
      w2 = __expf(lrelu(es.z + ed.z));
      w3 = __expf(lrelu(es.w + ed.w));
      z0 += w0; z1 += w1; z2 += w2; z3 += w3;
    }
    const int quads = (cnt + 3) >> 2;
#pragma unroll 2
    for (int p = 0; p < quads; ++p) {
      int ei = 4 * p + qt;                  // ei >= cnt -> broadcast w = 0
      int   sj = __shfl(s, ei);
      float b0 = __shfl(w0, ei), b1 = __shfl(w1, ei);
      float b2 = __shfl(w2, ei), b3 = __shfl(w3, ei);
      const float* xp = x + (size_t)sj * 128 + ql * 8;
      float4 f0 = *(const float4*)xp;
      float4 f1 = *(const float4*)(xp + 4);
      float fv[8] = {f0.x, f0.y, f0.z, f0.w, f1.x, f1.y, f1.z, f1.w};
#pragma unroll
      for (int k = 0; k < 8; ++k) {
        acc[0][k] += b0 * fv[k];
        acc[1][k] += b1 * fv[k];
        acc[2][k] += b2 * fv[k];
        acc[3][k] += b3 * fv[k];
      }
    }
  }
  // cross-quarter feature reduce
#pragma unroll
  for (int h = 0; h < 4; ++h)
#pragma unroll
    for (int k = 0; k < 8; ++k) {
      acc[h][k] += __shfl_xor(acc[h][k], 16);
      acc[h][k] += __shfl_xor(acc[h][k], 32);
    }
  // z full reduce
#pragma unroll
  for (int off = 1; off < 64; off <<= 1) {
    z0 += __shfl_xor(z0, off); z1 += __shfl_xor(z1, off);
    z2 += __shfl_xor(z2, off); z3 += __shfl_xor(z3, off);
  }
  // quarter qt handles head qt
  float zh = qt == 0 ? z0 : qt == 1 ? z1 : qt == 2 ? z2 : z3;
  float iz = 1.f / zh;
  float v[8];
#pragma unroll
  for (int k = 0; k < 8; ++k)
    v[k] = (qt == 0 ? acc[0][k] : qt == 1 ? acc[1][k] : qt == 2 ? acc[2][k] : acc[3][k]) * iz;
  ushort4 h0, l0, h1, l1;
  split_bf(v[0], h0.x, l0.x); split_bf(v[1], h0.y, l0.y);
  split_bf(v[2], h0.z, l0.z); split_bf(v[3], h0.w, l0.w);
  split_bf(v[4], h1.x, l1.x); split_bf(v[5], h1.y, l1.y);
  split_bf(v[6], h1.z, l1.z); split_bf(v[7], h1.w, l1.w);
  size_t o = (size_t)n * 512 + qt * 128 + ql * 8;
  *(ushort4*)(g_aggx_h + o) = h0; *(ushort4*)(g_aggx_h + o + 4) = h1;
  *(ushort4*)(g_aggx_l + o) = l0; *(ushort4*)(g_aggx_l + o + 4) = l1;
}

// ------- fused layer-1 expand + layer-2 GEMM, 64-row tiles ------------------
// Phase 1 reads A- and B-fragments DIRECTLY from global (no LDS staging, no
// barriers); only the h1 C->A layout transform round-trips through LDS
// (full-width 64x140-padded buffer, 2 barriers per head, 8 per block).
__global__ __launch_bounds__(256) void k_fused(const float* __restrict__ b1) {
  __shared__ unsigned short Hh[64 * 140];   // 17920 B
  __shared__ unsigned short Hl[64 * 140];   // 17920 B
  const int t = threadIdx.x;
  const int lane = t & 63, w = t >> 6;
  const int wrow = w >> 1, wcol = w & 1;
  const int ln15 = lane & 15, q = lane >> 4, qo = q * 8;
  const int row0 = blockIdx.y * 64;

  f4_t h2acc[2][4] = {};
#pragma unroll 1
  for (int h = 0; h < 4; ++h) {
    // ------- phase 1: h1acc = aggx_h @ W1_h  (all fragments from global) ----
    f4_t h1acc[2][4] = {};
#pragma unroll 2
    for (int ks = 0; ks < 128; ks += 32) {
      bf8_t ah[2], al[2];
#pragma unroll
      for (int i = 0; i < 2; ++i) {
        int r = row0 + wrow * 32 + i * 16 + ln15;
        ah[i] = bf8_zero(); al[i] = bf8_zero();
        if (r < kN) {
          size_t ga = (size_t)r * 512 + h * 128 + ks + qo;
          ah[i] = *(const bf8_t*)&g_aggx_h[ga];
          al[i] = *(const bf8_t*)&g_aggx_l[ga];
        }
      }
#pragma unroll
      for (int j = 0; j < 4; ++j) {
        size_t gb = ((size_t)h * 128 + wcol * 64 + j * 16 + ln15) * 128 + ks + qo;
        bf8_t bh = *(const bf8_t*)&g_w1t_h[gb];
        bf8_t bl = *(const bf8_t*)&g_w1t_l[gb];
#pragma unroll
        for (int i = 0; i < 2; ++i)
          h1acc[i][j] = __builtin_amdgcn_mfma_f32_16x16x32_bf16(ah[i], bh, h1acc[i][j], 0, 0, 0);
#pragma unroll
        for (int i = 0; i < 2; ++i)
          h1acc[i][j] = __builtin_amdgcn_mfma_f32_16x16x32_bf16(al[i], bh, h1acc[i][j], 0, 0, 0);
#pragma unroll
        for (int i = 0; i < 2; ++i)
          h1acc[i][j] = __builtin_amdgcn_mfma_f32_16x16x32_bf16(ah[i], bl, h1acc[i][j], 0, 0, 0);
      }
    }
    // ------- phase 2: bias + relu + split-bf16 ------------------------------
    unsigned pk[2][4][4];
#pragma unroll
    for (int j = 0; j < 4; ++j) {
      float bv = b1[h * 128 + wcol * 64 + j * 16 + ln15];
#pragma unroll
      for (int i = 0; i < 2; ++i)
#pragma unroll
        for (int reg = 0; reg < 4; ++reg) {
          float v = fmaxf(h1acc[i][j][reg] + bv, 0.f);
          unsigned short hb, lb;
          split_bf(v, hb, lb);
          pk[i][j][reg] = ((unsigned)hb << 16) | lb;
        }
    }
    // ------- phase 3: C->A transform via LDS, then h2 += h1_h @ W2_h --------
    __syncthreads();   // WAR: previous head's H reads complete
#pragma unroll
    for (int i = 0; i < 2; ++i)
#pragma unroll
      for (int j = 0; j < 4; ++j)
#pragma unroll
        for (int reg = 0; reg < 4; ++reg) {
          int rl = wrow * 32 + i * 16 + q * 4 + reg;
          int cl = wcol * 64 + j * 16 + ln15;
          Hh[rl * 140 + cl] = (unsigned short)(pk[i][j][reg] >> 16);
          Hl[rl * 140 + cl] = (unsigned short)(pk[i][j][reg] & 0xFFFFu);
        }
    __syncthreads();   // RAW: H fully written
#pragma unroll 2
    for (int kc = 0; kc < 128; kc += 32) {
      bf8_t ah[2], al[2];
#pragma unroll
      for (int i = 0; i < 2; ++i) {
        int ma = (wrow * 32 + i * 16 + ln15) * 140 + kc + qo;
        ah[i] = *(const bf8_t*)&Hh[ma];
        al[i] = *(const bf8_t*)&Hl[ma];
      }
#pragma unroll
      for (int j = 0; j < 4; ++j) {
        size_t gb = (size_t)(wcol * 64 + j * 16 + ln15) * 512 + h * 128 + kc + qo;
        bf8_t bh = *(const bf8_t*)&g_w2t_h[gb];
        bf8_t bl = *(const bf8_t*)&g_w2t_l[gb];
#pragma unroll
        for (int i = 0; i < 2; ++i)
          h2acc[i][j] = __builtin_amdgcn_mfma_f32_16x16x32_bf16(ah[i], bh, h2acc[i][j], 0, 0, 0);
#pragma unroll
        for (int i = 0; i < 2; ++i)
          h2acc[i][j] = __builtin_amdgcn_mfma_f32_16x16x32_bf16(al[i], bh, h2acc[i][j], 0, 0, 0);
#pragma unroll
        for (int i = 0; i < 2; ++i)
          h2acc[i][j] = __builtin_amdgcn_mfma_f32_16x16x32_bf16(ah[i], bl, h2acc[i][j], 0, 0, 0);
      }
    }
  }
  // ------- epilogue: write h2 (f32) -----------------------------------------
#pragma unroll
  for (int j = 0; j < 4; ++j) {
    int col = wcol * 64 + j * 16 + ln15;
#pragma unroll
    for (int i = 0; i < 2; ++i)
#pragma unroll
      for (int reg = 0; reg < 4; ++reg) {
        int r = row0 + wrow * 32 + i * 16 + q * 4 + reg;
        if (r < kN) g_h2[(size_t)r * 128 + col] = h2acc[i][j][reg];
      }
  }
}

// ---- layer-2 scores (reads h2 directly) ----
__global__ __launch_bounds__(256) void k_scores2(const float* __restrict__ asrc,
                                                 const float* __restrict__ adst) {
  const int lane = threadIdx.x & 63;
  const int n = (blockIdx.x * 256 + threadIdx.x) >> 6;
  if (n >= kN) return;
  const size_t o = (size_t)n * 128;
  float v0 = g_h2[o + lane];
  float v1 = g_h2[o + 64 + lane];
  float s = v0 * asrc[lane] + v1 * asrc[64 + lane];
  float d = v0 * adst[lane] + v1 * adst[64 + lane];
#pragma unroll
  for (int off = 32; off > 0; off >>= 1) {
    s += __shfl_down(s, off);
    d += __shfl_down(d, off);
  }
  if (lane == 0) { g_es2[n] = s; g_ed2[n] = d; }
}

// ---- layer-2 aggregation: 4 edges/iter (quarters) + fused FC ---------------
__global__ __launch_bounds__(256) void k_agg2x(const float* __restrict__ b2,
    const float* __restrict__ fcw, const float* __restrict__ fcb,
    float* __restrict__ out) {
  const int lane = threadIdx.x & 63;
  const int n = (blockIdx.x * 256 + threadIdx.x) >> 6;
  if (n >= kN) return;
  const int beg = g_ptr[n], end = g_ptr[n + 1];
  const float ed = g_ed2[n];
  const int qt = lane >> 4, ql = lane & 15;
  float zp = 0.f;
  float acc[8] = {};
  for (int base = beg; base < end; base += 64) {
    const int cnt = min(64, end - base);
    int s = 0; float w = 0.f;
    if (lane < cnt) {
      s = g_srcs[base + lane];
      w = __expf(lrelu(g_es2[s] + ed));
      zp += w;
    }
    const int quads = (cnt + 3) >> 2;
#pragma unroll 2
    for (int p = 0; p < quads; ++p) {
      int ei = 4 * p + qt;
      int   sj = __shfl(s, ei);
      float wj = __shfl(w, ei);
      const float* hp = g_h2 + (size_t)sj * 128 + ql * 8;
      float4 f0 = *(const float4*)hp;
      float4 f1 = *(const float4*)(hp + 4);
      acc[0] += wj * f0.x; acc[1] += wj * f0.y;
      acc[2] += wj * f0.z; acc[3] += wj * f0.w;
      acc[4] += wj * f1.x; acc[5] += wj * f1.y;
      acc[6] += wj * f1.z; acc[7] += wj * f1.w;
    }
  }
#pragma unroll
  for (int off = 1; off < 64; off <<= 1) zp += __shfl_xor(zp, off);
#pragma unroll
  for (int k = 0; k < 8; ++k) {
    acc[k] += __shfl_xor(acc[k], 16);
    acc[k] += __shfl_xor(acc[k], 32);
  }
  float invz = 1.f / zp;
  float s = 0.f;
#pragma unroll
  for (int k = 0; k < 8; ++k)
    s += (acc[k] * invz + b2[ql * 8 + k]) * fcw[ql * 8 + k];
#pragma unroll
  for (int off = 8; off > 0; off >>= 1) s += __shfl_xor(s, off);
  if (lane == 0) out[n] = s + fcb[0];
}

extern "C" void kernel_launch(void* const* d_in, const int* in_sizes, int n_in,
                              void* d_out, int out_size, void* d_ws, size_t ws_size,
                              hipStream_t stream) {
  const float* x   = (const float*)d_in[0];
  const int*   ei  = (const int*)d_in[1];
  const float* W1  = (const float*)d_in[2];
  const float* a1s = (const float*)d_in[3];
  const float* a1d = (const float*)d_in[4];
  const float* b1  = (const float*)d_in[5];
  const float* W2  = (const float*)d_in[6];
  const float* a2s = (const float*)d_in[7];
  const float* a2d = (const float*)d_in[8];
  const float* b2  = (const float*)d_in[9];
  const float* fcw = (const float*)d_in[10];
  const float* fcb = (const float*)d_in[11];
  float* out = (float*)d_out;
  (void)d_ws; (void)ws_size; (void)in_sizes; (void)n_in; (void)out_size;

  // ---- CSR build (dst-sorted) + weight conversion ----
  k_zero_deg<<<(kN + 255) / 256, 256, 0, stream>>>();
  k_hist<<<(kEt + 255) / 256, 256, 0, stream>>>(ei);
  k_scan<<<1, 1024, 0, stream>>>();
  k_scatter<<<(kEt + 255) / 256, 256, 0, stream>>>(ei);
  k_convw<<<512, 256, 0, stream>>>(W1, W2);

  // ---- layer 1 ----
  k_prep1<<<4, 256, 0, stream>>>(W1, a1s, a1d);
  k_scores1x<<<(kN * 64 + 255) / 256, 256, 0, stream>>>(x);
  k_agg1x<<<(kN * 64 + 255) / 256, 256, 0, stream>>>(x);

  // ---- fused expand + layer-2 GEMM (64-row tiles, barrier-light) ----
  dim3 gf(1, (kN + 63) / 64, 1);
  k_fused<<<gf, 256, 0, stream>>>(b1);

  // ---- layer 2 tail ----
  k_scores2<<<(kN * 64 + 255) / 256, 256, 0, stream>>>(a2s, a2d);
  k_agg2x<<<(kN * 64 + 255) / 256, 256, 0, stream>>>(b2, fcw, fcb, out);
}